// Round 7
// baseline (146.578 us; speedup 1.0000x reference)
//
#include <hip/hip_runtime.h>
#include <hip/hip_fp16.h>

// CRF NLL on MI355X — round 16: contention-free output reduction.
//
// r15 post-mortem: periodic norm confirmed the tail but only ~11us of the
// ~29us tail is the combine loop. The remainder: 512 blocks, running in
// lockstep (whole grid resident at t=0), all fire atomicAdd to ONE global
// f32 — ~512 serialized cross-XCD RMWs (~30-40ns each) = 15-20us of
// end-of-kernel drain (dispatch completes only when all memory ops retire).
//
// r16: per-block result -> atomicAdd into one of 64 bins (64B stride ->
// distinct cachelines, 8 blocks/bin in parallel), s_waitcnt vmcnt(0),
// atomic counter bump; the block drawing old==511 reads the 64 bins back
// with atomic-RMW reads (device-scope coherent; NO __threadfence — r8
// showed per-block fence L2-writeback is a disaster; atomics alone are
// coherent at the shared point), wave-reduces, plain-stores out.
// Bins+counter zeroed by stream-ordered memset each launch (graph-safe).
// Everything else byte-identical to r15.
//
// ws layout (dwords): [0, 16384) per-wave score/msum/napp slots (b*32+w*4);
//   [16384, 17408) 64 result bins (stride 16 dwords = 64B); [17408] counter.
//
// Scale 2^-6.5 per applied matrix (exact: added back as napp*6.5*ln2).

typedef __attribute__((ext_vector_type(8)))  _Float16 half8;
typedef __attribute__((ext_vector_type(2)))  _Float16 half2v;
typedef __attribute__((ext_vector_type(16))) float    f32x16;
typedef __attribute__((ext_vector_type(4)))  unsigned uint4v;

#define S_N 1024
#define T_N 32
#define B_N 512
#define L_CH 32
#define C_CH 32
#define SCALE_MUL 0.011048543456039806f   // 2^-6.5 folded into ee
#define SCALE_LOG 4.505456673639645f      // 6.5*ln2 per applied matrix

#define WS_BIN_OFF 16384                  // dword offset of 64 bins
#define WS_CNT_OFF 17408                  // dword offset of counter

__device__ __forceinline__ unsigned pkrtz(float lo, float hi) {
    return __builtin_bit_cast(unsigned, __builtin_amdgcn_cvt_pkrtz(lo, hi));
}
__device__ __forceinline__ unsigned pmul(unsigned a, unsigned b) {
    const __half2 r = __builtin_bit_cast(__half2, a) * __builtin_bit_cast(__half2, b);
    return __builtin_bit_cast(unsigned, r);
}
__device__ __forceinline__ half8 mkh8(const unsigned* a) {
    uint4v u = {a[0], a[1], a[2], a[3]};
    return __builtin_bit_cast(half8, u);
}
__device__ __forceinline__ float hlo(unsigned u) {
    return (float)__builtin_bit_cast(half2v, u).x;
}
__device__ __forceinline__ float hhi(unsigned u) {
    return (float)__builtin_bit_cast(half2v, u).y;
}
// PI: involution swapping rows 4-7<->8-11 and 20-23<->24-27
__device__ __forceinline__ int PIx(int x) { return (x & ~12) | ((x & 4) << 1) | ((x & 8) >> 1); }

__device__ __forceinline__ f32x16 packmm(const f32x16& D, uint4 su, uint4 sv,
                                         half8 A1v, half8 A2v) {
    unsigned S[8];
    S[0] = pmul(pkrtz(D[0],  D[1]),  su.x);
    S[1] = pmul(pkrtz(D[2],  D[3]),  su.y);
    S[2] = pmul(pkrtz(D[4],  D[5]),  su.z);
    S[3] = pmul(pkrtz(D[6],  D[7]),  su.w);
    S[4] = pmul(pkrtz(D[8],  D[9]),  sv.x);
    S[5] = pmul(pkrtz(D[10], D[11]), sv.y);
    S[6] = pmul(pkrtz(D[12], D[13]), sv.z);
    S[7] = pmul(pkrtz(D[14], D[15]), sv.w);
    const f32x16 Z = {};
    f32x16 t = __builtin_amdgcn_mfma_f32_32x32x16_f16(A1v, mkh8(&S[0]), Z, 0, 0, 0);
    return   __builtin_amdgcn_mfma_f32_32x32x16_f16(A2v, mkh8(&S[4]), t, 0, 0, 0);
}
__device__ __forceinline__ void step1(f32x16& D, const unsigned* mq, int r, int h,
                                      half8 A1v, half8 A2v) {
    const uint4 su = *(const uint4*)(mq + r * 16 + h * 8);
    const uint4 sv = *(const uint4*)(mq + r * 16 + h * 8 + 4);
    D = packmm(D, su, sv, A1v, A2v);
}

template<bool CLEAN>
__device__ __forceinline__ void chain2(const unsigned* m0, const unsigned* m1,
                                       f32x16& D0, f32x16& D1,
                                       unsigned mb0, unsigned mb1, int h,
                                       half8 A1v, half8 A2v) {
    if (CLEAN) {
        #pragma unroll 2
        for (int r = L_CH - 1; r >= 1; --r) {
            // all 4 loads issue back-to-back; chain1's packs fill chain0's MFMA shadow
            const uint4 su0 = *(const uint4*)(m0 + r * 16 + h * 8);
            const uint4 sv0 = *(const uint4*)(m0 + r * 16 + h * 8 + 4);
            const uint4 su1 = *(const uint4*)(m1 + r * 16 + h * 8);
            const uint4 sv1 = *(const uint4*)(m1 + r * 16 + h * 8 + 4);
            D0 = packmm(D0, su0, sv0, A1v, A2v);
            D1 = packmm(D1, su1, sv1, A1v, A2v);
        }
        if (mb0 & 1u) step1(D0, m0, 0, h, A1v, A2v);   // chunk 0 has bit0 cleared
        if (mb1 & 1u) step1(D1, m1, 0, h, A1v, A2v);
    } else {
        for (int r = L_CH - 1; r >= 0; --r) {
            if ((mb0 >> r) & 1u) step1(D0, m0, r, h, A1v, A2v);
            if ((mb1 >> r) & 1u) step1(D1, m1, r, h, A1v, A2v);
        }
    }
}

__global__ __attribute__((amdgpu_flat_work_group_size(512, 512),
                          amdgpu_waves_per_eu(4, 4)))
void crf_fused(
    const float* __restrict__ em, const int* __restrict__ tags,
    const float* __restrict__ mask, const float* __restrict__ trans,
    const float* __restrict__ startT, const float* __restrict__ endT,
    float* __restrict__ wspart, float* __restrict__ out)
{
    __shared__ unsigned elds[C_CH][512];   // 64 KiB: scales, reused for fragments

    const int wib  = threadIdx.x >> 6;     // 0..7
    const int lane = threadIdx.x & 63;
    const int n    = lane & 31;
    const int h    = lane >> 5;
    const int b    = blockIdx.x;
    const int c0   = wib * 4;              // this wave's first chunk

    // ---- issue pair-0 emission loads immediately (16B/lane, linear) ----
    float4 P0[4], P1[4];
    {
        const float4* eq0 = (const float4*)(em + ((size_t)b * S_N + (c0 + 0) * L_CH) * T_N);
        const float4* eq1 = (const float4*)(em + ((size_t)b * S_N + (c0 + 1) * L_CH) * T_N);
        #pragma unroll
        for (int i = 0; i < 4; ++i) P0[i] = eq0[i * 64 + lane];
        #pragma unroll
        for (int i = 0; i < 4; ++i) P1[i] = eq1[i * 64 + lane];
    }

    // ---- mask ballots (4 chunks = 128 positions) + path-score partial ----
    // (these scattered loads overlap the emission prefetch in flight)
    unsigned mb_[4];
    {
        float vacc = 0.f, macc = 0.f;
        #pragma unroll
        for (int q2 = 0; q2 < 2; ++q2) {
            const int s  = c0 * L_CH + q2 * 64 + lane;
            const float mv = mask[b * S_N + s];
            const unsigned long long mb = __ballot(mv != 0.0f);
            mb_[2 * q2]     = (unsigned)mb;
            mb_[2 * q2 + 1] = (unsigned)(mb >> 32);
            const int tc = tags[b * S_N + s];
            int tp = __shfl_up(tc, 1, 64);
            float val;
            if (lane == 0) {
                if (s == 0) {
                    val = startT[tc] + em[(size_t)b * S_N * T_N + tc];
                } else {
                    tp = tags[b * S_N + s - 1];
                    val = mv * (em[((size_t)b * S_N + s) * T_N + tc] + trans[tp * 32 + tc]);
                }
            } else {
                val = mv * (em[((size_t)b * S_N + s) * T_N + tc] + trans[tp * 32 + tc]);
            }
            vacc += val; macc += mv;
        }
        if (c0 == 0) mb_[0] &= ~1u;        // t=0 has no transition matrix
        #pragma unroll
        for (int d = 32; d > 0; d >>= 1) {
            vacc += __shfl_xor(vacc, d, 64);
            macc += __shfl_xor(macc, d, 64);
        }
        if (lane == 0) {
            float* slot = wspart + (size_t)b * 32 + wib * 4;
            slot[0] = vacc;
            slot[1] = macc;
            slot[2] = (float)(__popc(mb_[0]) + __popc(mb_[1]) +
                              __popc(mb_[2]) + __popc(mb_[3]));
        }
    }

    // ---- loop-invariant A fragments: f16(exp(trans)), PI-permuted cols ----
    unsigned A1[4], A2[4];
    #pragma unroll
    for (int j = 0; j < 4; ++j) {
        const int k1 = PIx(8 * h + 2 * j);
        const int k2 = PIx(16 + 8 * h + 2 * j);
        A1[j] = pkrtz(__expf(trans[n * 32 + k1]), __expf(trans[n * 32 + k1 + 1]));
        A2[j] = pkrtz(__expf(trans[n * 32 + k2]), __expf(trans[n * 32 + k2 + 1]));
    }
    const half8 A1v = mkh8(A1), A2v = mkh8(A2);

    // pack loaded f32 quads -> f16 scale pairs in D-reg-pair LDS order.
    // lane's float4 covers floats [f*4, f*4+3] of row r=f>>3; the two packed
    // u32s land at slots m and m+1, m = ((f&1)<<3)|(f&6)  (inverse of the
    // old per-slot base permutation) -> single 8B-aligned ds_write_b64.
    #define PACKQ(P, qc) { \
        unsigned* mq = elds[qc]; \
        _Pragma("unroll") \
        for (int i = 0; i < 4; ++i) { \
            const int f = i * 64 + lane; \
            const int r_ = f >> 3; \
            const int m_ = ((f & 1) << 3) | (f & 6); \
            const unsigned pk0 = pkrtz(__expf(P[i].x) * SCALE_MUL, __expf(P[i].y) * SCALE_MUL); \
            const unsigned pk1 = pkrtz(__expf(P[i].z) * SCALE_MUL, __expf(P[i].w) * SCALE_MUL); \
            *(uint2*)(mq + r_ * 16 + m_) = make_uint2(pk0, pk1); \
        } }

    PACKQ(P0, c0)
    PACKQ(P1, c0 + 1)

    // ---- issue pair-1 loads NOW; they fly under chain2(pair0) ----
    {
        const float4* eq2 = (const float4*)(em + ((size_t)b * S_N + (c0 + 2) * L_CH) * T_N);
        const float4* eq3 = (const float4*)(em + ((size_t)b * S_N + (c0 + 3) * L_CH) * T_N);
        #pragma unroll
        for (int i = 0; i < 4; ++i) P0[i] = eq2[i * 64 + lane];
        #pragma unroll
        for (int i = 0; i < 4; ++i) P1[i] = eq3[i * 64 + lane];
    }

    // ---- chain states: identity in C layout ----
    f32x16 D0, D1;
    #pragma unroll
    for (int i = 0; i < 16; ++i) {
        const int row = (i & 3) + 8 * (i >> 2) + 4 * h;
        const float v = (row == n) ? 1.0f : 0.0f;
        D0[i] = v; D1[i] = v;
    }

    const bool clean0 =
        ((mb_[0] | (c0 == 0 ? 1u : 0u)) == 0xFFFFFFFFu) && (mb_[1] == 0xFFFFFFFFu);
    const bool clean1 = (mb_[2] == 0xFFFFFFFFu) && (mb_[3] == 0xFFFFFFFFu);

    if (clean0) chain2<true >(elds[c0], elds[c0 + 1], D0, D1, mb_[0], mb_[1], h, A1v, A2v);
    else        chain2<false>(elds[c0], elds[c0 + 1], D0, D1, mb_[0], mb_[1], h, A1v, A2v);

    // fragment store: own LDS rows (scales dead), dense SoA, stride-16B
    #define STOREF(D, qc) { \
        unsigned* dst = elds[qc]; \
        ((uint4*)dst)[lane]      = make_uint4(pkrtz(D[0], D[1]),   pkrtz(D[2], D[3]), \
                                              pkrtz(D[4], D[5]),   pkrtz(D[6], D[7])); \
        ((uint4*)dst)[64 + lane] = make_uint4(pkrtz(D[8], D[9]),   pkrtz(D[10], D[11]), \
                                              pkrtz(D[12], D[13]), pkrtz(D[14], D[15])); \
    }
    STOREF(D0, c0) STOREF(D1, c0 + 1)

    // ---- pair 1: pack (consumes prefetch), re-init D, chain, store ----
    PACKQ(P0, c0 + 2)
    PACKQ(P1, c0 + 3)
    #pragma unroll
    for (int i = 0; i < 16; ++i) {
        const int row = (i & 3) + 8 * (i >> 2) + 4 * h;
        const float v = (row == n) ? 1.0f : 0.0f;
        D0[i] = v; D1[i] = v;
    }
    if (clean1) chain2<true >(elds[c0 + 2], elds[c0 + 3], D0, D1, mb_[2], mb_[3], h, A1v, A2v);
    else        chain2<false>(elds[c0 + 2], elds[c0 + 3], D0, D1, mb_[2], mb_[3], h, A1v, A2v);
    STOREF(D0, c0 + 2) STOREF(D1, c0 + 3)
    #undef STOREF
    #undef PACKQ

    __syncthreads();                        // all fragments + ws slots visible

    if (wib != 0) return;

    // ---- combine: 32-step alpha chain over LDS fragments ----
    // normalization every 4th iter, applied immediately (stable):
    // A<=1 after each norm; per-step growth <= ln(32*65504)=14.6 ln-units,
    // worst intermediate e^58.3 ~ 2e25 << f32 max. Lacc accumulates exactly
    // the applied logs. 24/32 iters skip the 5-deep shfl max + rcp + logf.
    int idxA[8], idxB[8];
    #pragma unroll
    for (int j = 0; j < 8; ++j) {
        idxA[j] = PIx(8 * h + j);
        idxB[j] = PIx(16 + 8 * h + j);
    }

    float a0 = startT[n] + em[(size_t)b * S_N * T_N + n];
    float mx = a0;
    #pragma unroll
    for (int d = 16; d > 0; d >>= 1) mx = fmaxf(mx, __shfl_xor(mx, d, 32));
    float A = __expf(a0 - mx);
    float Lacc = mx;
    float scor = (lane < 8) ? wspart[(size_t)b * 32 + lane * 4]     : 0.0f;
    float msum = (lane < 8) ? wspart[(size_t)b * 32 + lane * 4 + 1] : 0.0f;
    float ntot = (lane < 8) ? wspart[(size_t)b * 32 + lane * 4 + 2] : 0.0f;

    #pragma unroll 4
    for (int c = 0; c < C_CH; ++c) {
        const unsigned* ch = elds[c];
        const uint4 qa = *(const uint4*)(ch + lane * 4);
        const uint4 qb = *(const uint4*)(ch + 256 + lane * 4);

        float p0 = 0.f, p1 = 0.f, p2 = 0.f, p3 = 0.f;
        p0 = fmaf(__shfl(A, idxA[0], 32), hlo(qa.x), p0);
        p1 = fmaf(__shfl(A, idxA[1], 32), hhi(qa.x), p1);
        p2 = fmaf(__shfl(A, idxA[2], 32), hlo(qa.y), p2);
        p3 = fmaf(__shfl(A, idxA[3], 32), hhi(qa.y), p3);
        p0 = fmaf(__shfl(A, idxA[4], 32), hlo(qa.z), p0);
        p1 = fmaf(__shfl(A, idxA[5], 32), hhi(qa.z), p1);
        p2 = fmaf(__shfl(A, idxA[6], 32), hlo(qa.w), p2);
        p3 = fmaf(__shfl(A, idxA[7], 32), hhi(qa.w), p3);
        p0 = fmaf(__shfl(A, idxB[0], 32), hlo(qb.x), p0);
        p1 = fmaf(__shfl(A, idxB[1], 32), hhi(qb.x), p1);
        p2 = fmaf(__shfl(A, idxB[2], 32), hlo(qb.y), p2);
        p3 = fmaf(__shfl(A, idxB[3], 32), hhi(qb.y), p3);
        p0 = fmaf(__shfl(A, idxB[4], 32), hlo(qb.z), p0);
        p1 = fmaf(__shfl(A, idxB[5], 32), hhi(qb.z), p1);
        p2 = fmaf(__shfl(A, idxB[6], 32), hlo(qb.w), p2);
        p3 = fmaf(__shfl(A, idxB[7], 32), hhi(qb.w), p3);
        float part = (p0 + p1) + (p2 + p3);
        part += __shfl_xor(part, 32);       // fold half-wave partials

        if ((c & 3) == 3) {                 // static predicate (x4 unroll)
            float mm = part;
            #pragma unroll
            for (int d = 16; d > 0; d >>= 1) mm = fmaxf(mm, __shfl_xor(mm, d, 32));
            A = part * __builtin_amdgcn_rcpf(mm);
            Lacc += __logf(mm);
        } else {
            A = part;                       // unnormalized, hard-bounded
        }
    }

    float v = A * __expf(endT[n]);
    #pragma unroll
    for (int d = 16; d > 0; d >>= 1) {
        v    += __shfl_xor(v, d, 32);
        ntot += __shfl_xor(ntot, d, 32);
        msum += __shfl_xor(msum, d, 32);
        scor += __shfl_xor(scor, d, 32);
    }

    // ---- contention-free grid reduction: 64 bins + counter, last block sums ----
    int last = 0;
    if (lane == 0) {
        const int len = (int)(msum + 0.5f);
        const int lt  = tags[b * S_N + len - 1];
        const float res = Lacc + __logf(v) + ntot * SCALE_LOG - endT[lt] - scor;
        atomicAdd(&wspart[WS_BIN_OFF + (b & 63) * 16], res);
        asm volatile("s_waitcnt vmcnt(0)" ::: "memory");   // bin RMW retired first
        const unsigned old = atomicAdd((unsigned*)(wspart + WS_CNT_OFF), 1u);
        last = (old == (unsigned)(B_N - 1)) ? 1 : 0;
    }
    last = __shfl(last, 0, 64);
    if (last) {
        // atomic-RMW reads: device-scope coherent view of all 64 bins
        float x = atomicAdd(&wspart[WS_BIN_OFF + lane * 16], 0.0f);
        #pragma unroll
        for (int d = 32; d > 0; d >>= 1) x += __shfl_xor(x, d, 64);
        if (lane == 0) out[0] = x;
    }
}

extern "C" void kernel_launch(void* const* d_in, const int* in_sizes, int n_in,
                              void* d_out, int out_size, void* d_ws, size_t ws_size,
                              hipStream_t stream) {
    const float* em     = (const float*)d_in[0];
    const int*   tags   = (const int*)  d_in[1];
    const float* mask   = (const float*)d_in[2];
    const float* trans  = (const float*)d_in[3];
    const float* startT = (const float*)d_in[4];
    const float* endT   = (const float*)d_in[5];

    hipMemsetAsync(d_out, 0, sizeof(float), stream);
    // zero the 64 result bins + counter (stream-ordered, graph-safe)
    hipMemsetAsync((char*)d_ws + (size_t)WS_BIN_OFF * 4, 0,
                   (WS_CNT_OFF - WS_BIN_OFF + 16) * 4, stream);

    // one block per batch: 8 waves x 4 chunks; 64 KiB LDS -> 2 blocks/CU
    hipLaunchKernelGGL(crf_fused, dim3(B_N), dim3(512), 0, stream,
                       em, tags, mask, trans, startT, endT,
                       (float*)d_ws, (float*)d_out);
}

// Round 8
// 141.440 us; speedup vs baseline: 1.0363x; 1.0363x over previous
//
#include <hip/hip_runtime.h>
#include <hip/hip_fp16.h>

// CRF NLL on MI355X — round 17: REPLICATED-ALPHA combine (zero cross-lane).
//
// r16 post-mortem: bins+counter regressed (counter was equally contended) —
// reverted to r15's single atomicAdd. Tail re-derivation: occupancy math says
// tail ~33us but combine arithmetic is ~5us; the gap is the 16 per-iter
// ds_bpermute gathers (shfl with variable idx) each exposing ~100-150cy at
// VGPR=64 (allocator can't batch them; r13->r15's 5.1us for 24 removed
// max-reduces = ~100cy per shfl_xor confirms full exposed cross-lane cost).
//
// r17 combine: keep ALL 32 alpha values in registers in EVERY lane.
//   per iter: 4x ds_read_b128 (both halves of own column; PI row tables are
//   compile-time), 32 local FMA -> column sum; ds_write_b32 to abuf[32];
//   8x ds_read_b128 reload (uniform addr = broadcast, conflict-free).
//   Norm every 4th iter is LOCAL: 31 fmax over regs + rcp + logf.
//   No bpermute, no shfl, no divergence in the loop. ~300cy/iter vs ~2400.
// Pre-barrier phases byte-identical to r15. Single atomicAdd epilogue.
//
// Scale 2^-6.5 per applied matrix (exact: added back as napp*6.5*ln2).

typedef __attribute__((ext_vector_type(8)))  _Float16 half8;
typedef __attribute__((ext_vector_type(2)))  _Float16 half2v;
typedef __attribute__((ext_vector_type(16))) float    f32x16;
typedef __attribute__((ext_vector_type(4)))  unsigned uint4v;

#define S_N 1024
#define T_N 32
#define B_N 512
#define L_CH 32
#define C_CH 32
#define SCALE_MUL 0.011048543456039806f   // 2^-6.5 folded into ee
#define SCALE_LOG 4.505456673639645f      // 6.5*ln2 per applied matrix

__device__ __forceinline__ unsigned pkrtz(float lo, float hi) {
    return __builtin_bit_cast(unsigned, __builtin_amdgcn_cvt_pkrtz(lo, hi));
}
__device__ __forceinline__ unsigned pmul(unsigned a, unsigned b) {
    const __half2 r = __builtin_bit_cast(__half2, a) * __builtin_bit_cast(__half2, b);
    return __builtin_bit_cast(unsigned, r);
}
__device__ __forceinline__ half8 mkh8(const unsigned* a) {
    uint4v u = {a[0], a[1], a[2], a[3]};
    return __builtin_bit_cast(half8, u);
}
__device__ __forceinline__ float hlo(unsigned u) {
    return (float)__builtin_bit_cast(half2v, u).x;
}
__device__ __forceinline__ float hhi(unsigned u) {
    return (float)__builtin_bit_cast(half2v, u).y;
}
// PI: involution swapping rows 4-7<->8-11 and 20-23<->24-27
__device__ __forceinline__ int PIx(int x) { return (x & ~12) | ((x & 4) << 1) | ((x & 8) >> 1); }

__device__ __forceinline__ f32x16 packmm(const f32x16& D, uint4 su, uint4 sv,
                                         half8 A1v, half8 A2v) {
    unsigned S[8];
    S[0] = pmul(pkrtz(D[0],  D[1]),  su.x);
    S[1] = pmul(pkrtz(D[2],  D[3]),  su.y);
    S[2] = pmul(pkrtz(D[4],  D[5]),  su.z);
    S[3] = pmul(pkrtz(D[6],  D[7]),  su.w);
    S[4] = pmul(pkrtz(D[8],  D[9]),  sv.x);
    S[5] = pmul(pkrtz(D[10], D[11]), sv.y);
    S[6] = pmul(pkrtz(D[12], D[13]), sv.z);
    S[7] = pmul(pkrtz(D[14], D[15]), sv.w);
    const f32x16 Z = {};
    f32x16 t = __builtin_amdgcn_mfma_f32_32x32x16_f16(A1v, mkh8(&S[0]), Z, 0, 0, 0);
    return   __builtin_amdgcn_mfma_f32_32x32x16_f16(A2v, mkh8(&S[4]), t, 0, 0, 0);
}
__device__ __forceinline__ void step1(f32x16& D, const unsigned* mq, int r, int h,
                                      half8 A1v, half8 A2v) {
    const uint4 su = *(const uint4*)(mq + r * 16 + h * 8);
    const uint4 sv = *(const uint4*)(mq + r * 16 + h * 8 + 4);
    D = packmm(D, su, sv, A1v, A2v);
}

template<bool CLEAN>
__device__ __forceinline__ void chain2(const unsigned* m0, const unsigned* m1,
                                       f32x16& D0, f32x16& D1,
                                       unsigned mb0, unsigned mb1, int h,
                                       half8 A1v, half8 A2v) {
    if (CLEAN) {
        #pragma unroll 2
        for (int r = L_CH - 1; r >= 1; --r) {
            // all 4 loads issue back-to-back; chain1's packs fill chain0's MFMA shadow
            const uint4 su0 = *(const uint4*)(m0 + r * 16 + h * 8);
            const uint4 sv0 = *(const uint4*)(m0 + r * 16 + h * 8 + 4);
            const uint4 su1 = *(const uint4*)(m1 + r * 16 + h * 8);
            const uint4 sv1 = *(const uint4*)(m1 + r * 16 + h * 8 + 4);
            D0 = packmm(D0, su0, sv0, A1v, A2v);
            D1 = packmm(D1, su1, sv1, A1v, A2v);
        }
        if (mb0 & 1u) step1(D0, m0, 0, h, A1v, A2v);   // chunk 0 has bit0 cleared
        if (mb1 & 1u) step1(D1, m1, 0, h, A1v, A2v);
    } else {
        for (int r = L_CH - 1; r >= 0; --r) {
            if ((mb0 >> r) & 1u) step1(D0, m0, r, h, A1v, A2v);
            if ((mb1 >> r) & 1u) step1(D1, m1, r, h, A1v, A2v);
        }
    }
}

__global__ __attribute__((amdgpu_flat_work_group_size(512, 512),
                          amdgpu_waves_per_eu(4, 4)))
void crf_fused(
    const float* __restrict__ em, const int* __restrict__ tags,
    const float* __restrict__ mask, const float* __restrict__ trans,
    const float* __restrict__ startT, const float* __restrict__ endT,
    float* __restrict__ wspart, float* __restrict__ out)
{
    __shared__ unsigned elds[C_CH][512];   // 64 KiB: scales, reused for fragments
    __shared__ float abuf[32];             // alpha broadcast buffer (combine)

    const int wib  = threadIdx.x >> 6;     // 0..7
    const int lane = threadIdx.x & 63;
    const int n    = lane & 31;
    const int h    = lane >> 5;
    const int b    = blockIdx.x;
    const int c0   = wib * 4;              // this wave's first chunk

    // ---- issue pair-0 emission loads immediately (16B/lane, linear) ----
    float4 P0[4], P1[4];
    {
        const float4* eq0 = (const float4*)(em + ((size_t)b * S_N + (c0 + 0) * L_CH) * T_N);
        const float4* eq1 = (const float4*)(em + ((size_t)b * S_N + (c0 + 1) * L_CH) * T_N);
        #pragma unroll
        for (int i = 0; i < 4; ++i) P0[i] = eq0[i * 64 + lane];
        #pragma unroll
        for (int i = 0; i < 4; ++i) P1[i] = eq1[i * 64 + lane];
    }

    // ---- mask ballots (4 chunks = 128 positions) + path-score partial ----
    unsigned mb_[4];
    {
        float vacc = 0.f, macc = 0.f;
        #pragma unroll
        for (int q2 = 0; q2 < 2; ++q2) {
            const int s  = c0 * L_CH + q2 * 64 + lane;
            const float mv = mask[b * S_N + s];
            const unsigned long long mb = __ballot(mv != 0.0f);
            mb_[2 * q2]     = (unsigned)mb;
            mb_[2 * q2 + 1] = (unsigned)(mb >> 32);
            const int tc = tags[b * S_N + s];
            int tp = __shfl_up(tc, 1, 64);
            float val;
            if (lane == 0) {
                if (s == 0) {
                    val = startT[tc] + em[(size_t)b * S_N * T_N + tc];
                } else {
                    tp = tags[b * S_N + s - 1];
                    val = mv * (em[((size_t)b * S_N + s) * T_N + tc] + trans[tp * 32 + tc]);
                }
            } else {
                val = mv * (em[((size_t)b * S_N + s) * T_N + tc] + trans[tp * 32 + tc]);
            }
            vacc += val; macc += mv;
        }
        if (c0 == 0) mb_[0] &= ~1u;        // t=0 has no transition matrix
        #pragma unroll
        for (int d = 32; d > 0; d >>= 1) {
            vacc += __shfl_xor(vacc, d, 64);
            macc += __shfl_xor(macc, d, 64);
        }
        if (lane == 0) {
            float* slot = wspart + (size_t)b * 32 + wib * 4;
            slot[0] = vacc;
            slot[1] = macc;
            slot[2] = (float)(__popc(mb_[0]) + __popc(mb_[1]) +
                              __popc(mb_[2]) + __popc(mb_[3]));
        }
    }

    // ---- loop-invariant A fragments: f16(exp(trans)), PI-permuted cols ----
    unsigned A1[4], A2[4];
    #pragma unroll
    for (int j = 0; j < 4; ++j) {
        const int k1 = PIx(8 * h + 2 * j);
        const int k2 = PIx(16 + 8 * h + 2 * j);
        A1[j] = pkrtz(__expf(trans[n * 32 + k1]), __expf(trans[n * 32 + k1 + 1]));
        A2[j] = pkrtz(__expf(trans[n * 32 + k2]), __expf(trans[n * 32 + k2 + 1]));
    }
    const half8 A1v = mkh8(A1), A2v = mkh8(A2);

    // pack loaded f32 quads -> f16 scale pairs in D-reg-pair LDS order.
    #define PACKQ(P, qc) { \
        unsigned* mq = elds[qc]; \
        _Pragma("unroll") \
        for (int i = 0; i < 4; ++i) { \
            const int f = i * 64 + lane; \
            const int r_ = f >> 3; \
            const int m_ = ((f & 1) << 3) | (f & 6); \
            const unsigned pk0 = pkrtz(__expf(P[i].x) * SCALE_MUL, __expf(P[i].y) * SCALE_MUL); \
            const unsigned pk1 = pkrtz(__expf(P[i].z) * SCALE_MUL, __expf(P[i].w) * SCALE_MUL); \
            *(uint2*)(mq + r_ * 16 + m_) = make_uint2(pk0, pk1); \
        } }

    PACKQ(P0, c0)
    PACKQ(P1, c0 + 1)

    // ---- issue pair-1 loads NOW; they fly under chain2(pair0) ----
    {
        const float4* eq2 = (const float4*)(em + ((size_t)b * S_N + (c0 + 2) * L_CH) * T_N);
        const float4* eq3 = (const float4*)(em + ((size_t)b * S_N + (c0 + 3) * L_CH) * T_N);
        #pragma unroll
        for (int i = 0; i < 4; ++i) P0[i] = eq2[i * 64 + lane];
        #pragma unroll
        for (int i = 0; i < 4; ++i) P1[i] = eq3[i * 64 + lane];
    }

    // ---- chain states: identity in C layout ----
    f32x16 D0, D1;
    #pragma unroll
    for (int i = 0; i < 16; ++i) {
        const int row = (i & 3) + 8 * (i >> 2) + 4 * h;
        const float v = (row == n) ? 1.0f : 0.0f;
        D0[i] = v; D1[i] = v;
    }

    const bool clean0 =
        ((mb_[0] | (c0 == 0 ? 1u : 0u)) == 0xFFFFFFFFu) && (mb_[1] == 0xFFFFFFFFu);
    const bool clean1 = (mb_[2] == 0xFFFFFFFFu) && (mb_[3] == 0xFFFFFFFFu);

    if (clean0) chain2<true >(elds[c0], elds[c0 + 1], D0, D1, mb_[0], mb_[1], h, A1v, A2v);
    else        chain2<false>(elds[c0], elds[c0 + 1], D0, D1, mb_[0], mb_[1], h, A1v, A2v);

    // fragment store: own LDS rows (scales dead), dense SoA, stride-16B
    #define STOREF(D, qc) { \
        unsigned* dst = elds[qc]; \
        ((uint4*)dst)[lane]      = make_uint4(pkrtz(D[0], D[1]),   pkrtz(D[2], D[3]), \
                                              pkrtz(D[4], D[5]),   pkrtz(D[6], D[7])); \
        ((uint4*)dst)[64 + lane] = make_uint4(pkrtz(D[8], D[9]),   pkrtz(D[10], D[11]), \
                                              pkrtz(D[12], D[13]), pkrtz(D[14], D[15])); \
    }
    STOREF(D0, c0) STOREF(D1, c0 + 1)

    // ---- pair 1: pack (consumes prefetch), re-init D, chain, store ----
    PACKQ(P0, c0 + 2)
    PACKQ(P1, c0 + 3)
    #pragma unroll
    for (int i = 0; i < 16; ++i) {
        const int row = (i & 3) + 8 * (i >> 2) + 4 * h;
        const float v = (row == n) ? 1.0f : 0.0f;
        D0[i] = v; D1[i] = v;
    }
    if (clean1) chain2<true >(elds[c0 + 2], elds[c0 + 3], D0, D1, mb_[2], mb_[3], h, A1v, A2v);
    else        chain2<false>(elds[c0 + 2], elds[c0 + 3], D0, D1, mb_[2], mb_[3], h, A1v, A2v);
    STOREF(D0, c0 + 2) STOREF(D1, c0 + 3)
    #undef STOREF
    #undef PACKQ

    __syncthreads();                        // all fragments + ws slots visible

    if (wib != 0) return;

    // ---- combine: replicated-alpha chain, zero cross-lane in the loop ----
    float scor = (lane < 8) ? wspart[(size_t)b * 32 + lane * 4]     : 0.0f;
    float msum = (lane < 8) ? wspart[(size_t)b * 32 + lane * 4 + 1] : 0.0f;
    float ntot = (lane < 8) ? wspart[(size_t)b * 32 + lane * 4 + 2] : 0.0f;

    // init: replicate a0 via abuf (both halves write identical values)
    float Ar[32];
    {
        const float a0 = startT[n] + em[(size_t)b * S_N * T_N + n];
        abuf[n] = a0;
        #pragma unroll
        for (int k = 0; k < 8; ++k) {
            const float4 t = *(const float4*)&abuf[k * 4];
            Ar[4 * k] = t.x; Ar[4 * k + 1] = t.y; Ar[4 * k + 2] = t.z; Ar[4 * k + 3] = t.w;
        }
    }
    float mx = Ar[0];
    #pragma unroll
    for (int r = 1; r < 32; ++r) mx = fmaxf(mx, Ar[r]);
    float Lacc = mx;
    #pragma unroll
    for (int r = 0; r < 32; ++r) Ar[r] = __expf(Ar[r] - mx);

    // row tables are compile-time: fragment half j of quad q, half-block hh
    // covers row (j&3) + 8*(j>>2) + 4*hh + 16*q  (PI already folded in).
    #define ACC8(f, B) { \
        p0 = fmaf(Ar[(B) + 0],  hlo((f).x), p0); \
        p1 = fmaf(Ar[(B) + 1],  hhi((f).x), p1); \
        p2 = fmaf(Ar[(B) + 2],  hlo((f).y), p2); \
        p3 = fmaf(Ar[(B) + 3],  hhi((f).y), p3); \
        p0 = fmaf(Ar[(B) + 8],  hlo((f).z), p0); \
        p1 = fmaf(Ar[(B) + 9],  hhi((f).z), p1); \
        p2 = fmaf(Ar[(B) + 10], hlo((f).w), p2); \
        p3 = fmaf(Ar[(B) + 11], hhi((f).w), p3); }

    for (int cc = 0; cc < 8; ++cc) {        // outer: no unroll (reg pressure)
        #pragma unroll
        for (int k = 0; k < 4; ++k) {       // inner: full unroll, static norm
            const unsigned* ch = elds[cc * 4 + k];
            const uint4 f00 = *(const uint4*)(ch + n * 4);              // q0 h0
            const uint4 f01 = *(const uint4*)(ch + (n + 32) * 4);       // q0 h1
            const uint4 f10 = *(const uint4*)(ch + 256 + n * 4);        // q1 h0
            const uint4 f11 = *(const uint4*)(ch + 256 + (n + 32) * 4); // q1 h1

            float p0 = 0.f, p1 = 0.f, p2 = 0.f, p3 = 0.f;
            ACC8(f00, 0)  ACC8(f01, 4)  ACC8(f10, 16) ACC8(f11, 20)
            const float part = (p0 + p1) + (p2 + p3);   // full column sum

            abuf[n] = part;                 // broadcast (same-wave, in-order DS)
            #pragma unroll
            for (int kk = 0; kk < 8; ++kk) {
                const float4 t = *(const float4*)&abuf[kk * 4];
                Ar[4 * kk] = t.x; Ar[4 * kk + 1] = t.y;
                Ar[4 * kk + 2] = t.z; Ar[4 * kk + 3] = t.w;
            }
            if (k == 3) {                   // local norm: no cross-lane
                float mm = Ar[0];
                #pragma unroll
                for (int r = 1; r < 32; ++r) mm = fmaxf(mm, Ar[r]);
                const float rn = __builtin_amdgcn_rcpf(mm);
                #pragma unroll
                for (int r = 0; r < 32; ++r) Ar[r] *= rn;
                Lacc += __logf(mm);
            }
        }
    }
    #undef ACC8

    // z = sum_r Ar[r] * exp(endT[r])  — wave-uniform loads, fully local
    float z = 0.f;
    #pragma unroll
    for (int k = 0; k < 8; ++k) {
        const float4 t = *(const float4*)&endT[k * 4];
        z = fmaf(Ar[4 * k],     __expf(t.x), z);
        z = fmaf(Ar[4 * k + 1], __expf(t.y), z);
        z = fmaf(Ar[4 * k + 2], __expf(t.z), z);
        z = fmaf(Ar[4 * k + 3], __expf(t.w), z);
    }

    #pragma unroll
    for (int d = 16; d > 0; d >>= 1) {
        ntot += __shfl_xor(ntot, d, 32);
        msum += __shfl_xor(msum, d, 32);
        scor += __shfl_xor(scor, d, 32);
    }
    if (lane == 0) {
        const int len = (int)(msum + 0.5f);
        const int lt  = tags[b * S_N + len - 1];
        const float res = Lacc + __logf(z) + ntot * SCALE_LOG - endT[lt] - scor;
        atomicAdd(out, res);
    }
}

extern "C" void kernel_launch(void* const* d_in, const int* in_sizes, int n_in,
                              void* d_out, int out_size, void* d_ws, size_t ws_size,
                              hipStream_t stream) {
    const float* em     = (const float*)d_in[0];
    const int*   tags   = (const int*)  d_in[1];
    const float* mask   = (const float*)d_in[2];
    const float* trans  = (const float*)d_in[3];
    const float* startT = (const float*)d_in[4];
    const float* endT   = (const float*)d_in[5];

    hipMemsetAsync(d_out, 0, sizeof(float), stream);

    // one block per batch: 8 waves x 4 chunks; 64 KiB LDS -> 2 blocks/CU
    hipLaunchKernelGGL(crf_fused, dim3(B_N), dim3(512), 0, stream,
                       em, tags, mask, trans, startT, endT,
                       (float*)d_ws, (float*)d_out);
}

// Round 9
// 139.255 us; speedup vs baseline: 1.0526x; 1.0157x over previous
//
#include <hip/hip_runtime.h>
#include <hip/hip_fp16.h>

// CRF NLL on MI355X — round 18: kill the contended-atomic drain (clean test).
//
// r17 post-mortem: combine rewrite removed the spill (WRITE 2.1MB->84KB) but
// kernel stayed ~56us; occupancy identity still shows ~half the kernel at
// ~zero residency. Only candidate with that signature left: the epilogue's
// 512 lockstep atomicAdds to ONE global f32 — serialized coherence-point
// RMWs (~30-50ns each ~ 15-25us) draining after all waves exited. r16 never
// tested this (it added an equally-contended counter + vmcnt(0)).
//
// r18: each block PLAIN-STORES res to ws[b] (512 distinct addresses, zero
// contention); a second 1-wave kernel sums the 512 floats and writes out.
// Stream order guarantees cross-kernel visibility. No atomics, no counter,
// no fences. Everything else byte-identical to r17 for clean attribution.
//
// ws layout (dwords): [0,16384) per-wave score/msum/napp slots (b*32+w*4);
//   [16384, 16896) per-block results.
//
// Scale 2^-6.5 per applied matrix (exact: added back as napp*6.5*ln2).

typedef __attribute__((ext_vector_type(8)))  _Float16 half8;
typedef __attribute__((ext_vector_type(2)))  _Float16 half2v;
typedef __attribute__((ext_vector_type(16))) float    f32x16;
typedef __attribute__((ext_vector_type(4)))  unsigned uint4v;

#define S_N 1024
#define T_N 32
#define B_N 512
#define L_CH 32
#define C_CH 32
#define SCALE_MUL 0.011048543456039806f   // 2^-6.5 folded into ee
#define SCALE_LOG 4.505456673639645f      // 6.5*ln2 per applied matrix

#define WS_RES_OFF 16384                  // dword offset of per-block results

__device__ __forceinline__ unsigned pkrtz(float lo, float hi) {
    return __builtin_bit_cast(unsigned, __builtin_amdgcn_cvt_pkrtz(lo, hi));
}
__device__ __forceinline__ unsigned pmul(unsigned a, unsigned b) {
    const __half2 r = __builtin_bit_cast(__half2, a) * __builtin_bit_cast(__half2, b);
    return __builtin_bit_cast(unsigned, r);
}
__device__ __forceinline__ half8 mkh8(const unsigned* a) {
    uint4v u = {a[0], a[1], a[2], a[3]};
    return __builtin_bit_cast(half8, u);
}
__device__ __forceinline__ float hlo(unsigned u) {
    return (float)__builtin_bit_cast(half2v, u).x;
}
__device__ __forceinline__ float hhi(unsigned u) {
    return (float)__builtin_bit_cast(half2v, u).y;
}
// PI: involution swapping rows 4-7<->8-11 and 20-23<->24-27
__device__ __forceinline__ int PIx(int x) { return (x & ~12) | ((x & 4) << 1) | ((x & 8) >> 1); }

__device__ __forceinline__ f32x16 packmm(const f32x16& D, uint4 su, uint4 sv,
                                         half8 A1v, half8 A2v) {
    unsigned S[8];
    S[0] = pmul(pkrtz(D[0],  D[1]),  su.x);
    S[1] = pmul(pkrtz(D[2],  D[3]),  su.y);
    S[2] = pmul(pkrtz(D[4],  D[5]),  su.z);
    S[3] = pmul(pkrtz(D[6],  D[7]),  su.w);
    S[4] = pmul(pkrtz(D[8],  D[9]),  sv.x);
    S[5] = pmul(pkrtz(D[10], D[11]), sv.y);
    S[6] = pmul(pkrtz(D[12], D[13]), sv.z);
    S[7] = pmul(pkrtz(D[14], D[15]), sv.w);
    const f32x16 Z = {};
    f32x16 t = __builtin_amdgcn_mfma_f32_32x32x16_f16(A1v, mkh8(&S[0]), Z, 0, 0, 0);
    return   __builtin_amdgcn_mfma_f32_32x32x16_f16(A2v, mkh8(&S[4]), t, 0, 0, 0);
}
__device__ __forceinline__ void step1(f32x16& D, const unsigned* mq, int r, int h,
                                      half8 A1v, half8 A2v) {
    const uint4 su = *(const uint4*)(mq + r * 16 + h * 8);
    const uint4 sv = *(const uint4*)(mq + r * 16 + h * 8 + 4);
    D = packmm(D, su, sv, A1v, A2v);
}

template<bool CLEAN>
__device__ __forceinline__ void chain2(const unsigned* m0, const unsigned* m1,
                                       f32x16& D0, f32x16& D1,
                                       unsigned mb0, unsigned mb1, int h,
                                       half8 A1v, half8 A2v) {
    if (CLEAN) {
        #pragma unroll 2
        for (int r = L_CH - 1; r >= 1; --r) {
            // all 4 loads issue back-to-back; chain1's packs fill chain0's MFMA shadow
            const uint4 su0 = *(const uint4*)(m0 + r * 16 + h * 8);
            const uint4 sv0 = *(const uint4*)(m0 + r * 16 + h * 8 + 4);
            const uint4 su1 = *(const uint4*)(m1 + r * 16 + h * 8);
            const uint4 sv1 = *(const uint4*)(m1 + r * 16 + h * 8 + 4);
            D0 = packmm(D0, su0, sv0, A1v, A2v);
            D1 = packmm(D1, su1, sv1, A1v, A2v);
        }
        if (mb0 & 1u) step1(D0, m0, 0, h, A1v, A2v);   // chunk 0 has bit0 cleared
        if (mb1 & 1u) step1(D1, m1, 0, h, A1v, A2v);
    } else {
        for (int r = L_CH - 1; r >= 0; --r) {
            if ((mb0 >> r) & 1u) step1(D0, m0, r, h, A1v, A2v);
            if ((mb1 >> r) & 1u) step1(D1, m1, r, h, A1v, A2v);
        }
    }
}

__global__ __attribute__((amdgpu_flat_work_group_size(512, 512),
                          amdgpu_waves_per_eu(4, 4)))
void crf_fused(
    const float* __restrict__ em, const int* __restrict__ tags,
    const float* __restrict__ mask, const float* __restrict__ trans,
    const float* __restrict__ startT, const float* __restrict__ endT,
    float* __restrict__ wspart, float* __restrict__ out)
{
    __shared__ unsigned elds[C_CH][512];   // 64 KiB: scales, reused for fragments
    __shared__ float abuf[32];             // alpha broadcast buffer (combine)

    const int wib  = threadIdx.x >> 6;     // 0..7
    const int lane = threadIdx.x & 63;
    const int n    = lane & 31;
    const int h    = lane >> 5;
    const int b    = blockIdx.x;
    const int c0   = wib * 4;              // this wave's first chunk

    // ---- issue pair-0 emission loads immediately (16B/lane, linear) ----
    float4 P0[4], P1[4];
    {
        const float4* eq0 = (const float4*)(em + ((size_t)b * S_N + (c0 + 0) * L_CH) * T_N);
        const float4* eq1 = (const float4*)(em + ((size_t)b * S_N + (c0 + 1) * L_CH) * T_N);
        #pragma unroll
        for (int i = 0; i < 4; ++i) P0[i] = eq0[i * 64 + lane];
        #pragma unroll
        for (int i = 0; i < 4; ++i) P1[i] = eq1[i * 64 + lane];
    }

    // ---- mask ballots (4 chunks = 128 positions) + path-score partial ----
    unsigned mb_[4];
    {
        float vacc = 0.f, macc = 0.f;
        #pragma unroll
        for (int q2 = 0; q2 < 2; ++q2) {
            const int s  = c0 * L_CH + q2 * 64 + lane;
            const float mv = mask[b * S_N + s];
            const unsigned long long mb = __ballot(mv != 0.0f);
            mb_[2 * q2]     = (unsigned)mb;
            mb_[2 * q2 + 1] = (unsigned)(mb >> 32);
            const int tc = tags[b * S_N + s];
            int tp = __shfl_up(tc, 1, 64);
            float val;
            if (lane == 0) {
                if (s == 0) {
                    val = startT[tc] + em[(size_t)b * S_N * T_N + tc];
                } else {
                    tp = tags[b * S_N + s - 1];
                    val = mv * (em[((size_t)b * S_N + s) * T_N + tc] + trans[tp * 32 + tc]);
                }
            } else {
                val = mv * (em[((size_t)b * S_N + s) * T_N + tc] + trans[tp * 32 + tc]);
            }
            vacc += val; macc += mv;
        }
        if (c0 == 0) mb_[0] &= ~1u;        // t=0 has no transition matrix
        #pragma unroll
        for (int d = 32; d > 0; d >>= 1) {
            vacc += __shfl_xor(vacc, d, 64);
            macc += __shfl_xor(macc, d, 64);
        }
        if (lane == 0) {
            float* slot = wspart + (size_t)b * 32 + wib * 4;
            slot[0] = vacc;
            slot[1] = macc;
            slot[2] = (float)(__popc(mb_[0]) + __popc(mb_[1]) +
                              __popc(mb_[2]) + __popc(mb_[3]));
        }
    }

    // ---- loop-invariant A fragments: f16(exp(trans)), PI-permuted cols ----
    unsigned A1[4], A2[4];
    #pragma unroll
    for (int j = 0; j < 4; ++j) {
        const int k1 = PIx(8 * h + 2 * j);
        const int k2 = PIx(16 + 8 * h + 2 * j);
        A1[j] = pkrtz(__expf(trans[n * 32 + k1]), __expf(trans[n * 32 + k1 + 1]));
        A2[j] = pkrtz(__expf(trans[n * 32 + k2]), __expf(trans[n * 32 + k2 + 1]));
    }
    const half8 A1v = mkh8(A1), A2v = mkh8(A2);

    // pack loaded f32 quads -> f16 scale pairs in D-reg-pair LDS order.
    #define PACKQ(P, qc) { \
        unsigned* mq = elds[qc]; \
        _Pragma("unroll") \
        for (int i = 0; i < 4; ++i) { \
            const int f = i * 64 + lane; \
            const int r_ = f >> 3; \
            const int m_ = ((f & 1) << 3) | (f & 6); \
            const unsigned pk0 = pkrtz(__expf(P[i].x) * SCALE_MUL, __expf(P[i].y) * SCALE_MUL); \
            const unsigned pk1 = pkrtz(__expf(P[i].z) * SCALE_MUL, __expf(P[i].w) * SCALE_MUL); \
            *(uint2*)(mq + r_ * 16 + m_) = make_uint2(pk0, pk1); \
        } }

    PACKQ(P0, c0)
    PACKQ(P1, c0 + 1)

    // ---- issue pair-1 loads NOW; they fly under chain2(pair0) ----
    {
        const float4* eq2 = (const float4*)(em + ((size_t)b * S_N + (c0 + 2) * L_CH) * T_N);
        const float4* eq3 = (const float4*)(em + ((size_t)b * S_N + (c0 + 3) * L_CH) * T_N);
        #pragma unroll
        for (int i = 0; i < 4; ++i) P0[i] = eq2[i * 64 + lane];
        #pragma unroll
        for (int i = 0; i < 4; ++i) P1[i] = eq3[i * 64 + lane];
    }

    // ---- chain states: identity in C layout ----
    f32x16 D0, D1;
    #pragma unroll
    for (int i = 0; i < 16; ++i) {
        const int row = (i & 3) + 8 * (i >> 2) + 4 * h;
        const float v = (row == n) ? 1.0f : 0.0f;
        D0[i] = v; D1[i] = v;
    }

    const bool clean0 =
        ((mb_[0] | (c0 == 0 ? 1u : 0u)) == 0xFFFFFFFFu) && (mb_[1] == 0xFFFFFFFFu);
    const bool clean1 = (mb_[2] == 0xFFFFFFFFu) && (mb_[3] == 0xFFFFFFFFu);

    if (clean0) chain2<true >(elds[c0], elds[c0 + 1], D0, D1, mb_[0], mb_[1], h, A1v, A2v);
    else        chain2<false>(elds[c0], elds[c0 + 1], D0, D1, mb_[0], mb_[1], h, A1v, A2v);

    // fragment store: own LDS rows (scales dead), dense SoA, stride-16B
    #define STOREF(D, qc) { \
        unsigned* dst = elds[qc]; \
        ((uint4*)dst)[lane]      = make_uint4(pkrtz(D[0], D[1]),   pkrtz(D[2], D[3]), \
                                              pkrtz(D[4], D[5]),   pkrtz(D[6], D[7])); \
        ((uint4*)dst)[64 + lane] = make_uint4(pkrtz(D[8], D[9]),   pkrtz(D[10], D[11]), \
                                              pkrtz(D[12], D[13]), pkrtz(D[14], D[15])); \
    }
    STOREF(D0, c0) STOREF(D1, c0 + 1)

    // ---- pair 1: pack (consumes prefetch), re-init D, chain, store ----
    PACKQ(P0, c0 + 2)
    PACKQ(P1, c0 + 3)
    #pragma unroll
    for (int i = 0; i < 16; ++i) {
        const int row = (i & 3) + 8 * (i >> 2) + 4 * h;
        const float v = (row == n) ? 1.0f : 0.0f;
        D0[i] = v; D1[i] = v;
    }
    if (clean1) chain2<true >(elds[c0 + 2], elds[c0 + 3], D0, D1, mb_[2], mb_[3], h, A1v, A2v);
    else        chain2<false>(elds[c0 + 2], elds[c0 + 3], D0, D1, mb_[2], mb_[3], h, A1v, A2v);
    STOREF(D0, c0 + 2) STOREF(D1, c0 + 3)
    #undef STOREF
    #undef PACKQ

    __syncthreads();                        // all fragments + ws slots visible

    if (wib != 0) return;

    // ---- combine: replicated-alpha chain, zero cross-lane in the loop ----
    float scor = (lane < 8) ? wspart[(size_t)b * 32 + lane * 4]     : 0.0f;
    float msum = (lane < 8) ? wspart[(size_t)b * 32 + lane * 4 + 1] : 0.0f;
    float ntot = (lane < 8) ? wspart[(size_t)b * 32 + lane * 4 + 2] : 0.0f;

    // init: replicate a0 via abuf (both halves write identical values)
    float Ar[32];
    {
        const float a0 = startT[n] + em[(size_t)b * S_N * T_N + n];
        abuf[n] = a0;
        #pragma unroll
        for (int k = 0; k < 8; ++k) {
            const float4 t = *(const float4*)&abuf[k * 4];
            Ar[4 * k] = t.x; Ar[4 * k + 1] = t.y; Ar[4 * k + 2] = t.z; Ar[4 * k + 3] = t.w;
        }
    }
    float mx = Ar[0];
    #pragma unroll
    for (int r = 1; r < 32; ++r) mx = fmaxf(mx, Ar[r]);
    float Lacc = mx;
    #pragma unroll
    for (int r = 0; r < 32; ++r) Ar[r] = __expf(Ar[r] - mx);

    // row tables are compile-time: fragment half j of quad q, half-block hh
    // covers row (j&3) + 8*(j>>2) + 4*hh + 16*q  (PI already folded in).
    #define ACC8(f, B) { \
        p0 = fmaf(Ar[(B) + 0],  hlo((f).x), p0); \
        p1 = fmaf(Ar[(B) + 1],  hhi((f).x), p1); \
        p2 = fmaf(Ar[(B) + 2],  hlo((f).y), p2); \
        p3 = fmaf(Ar[(B) + 3],  hhi((f).y), p3); \
        p0 = fmaf(Ar[(B) + 8],  hlo((f).z), p0); \
        p1 = fmaf(Ar[(B) + 9],  hhi((f).z), p1); \
        p2 = fmaf(Ar[(B) + 10], hlo((f).w), p2); \
        p3 = fmaf(Ar[(B) + 11], hhi((f).w), p3); }

    for (int cc = 0; cc < 8; ++cc) {        // outer: no unroll (reg pressure)
        #pragma unroll
        for (int k = 0; k < 4; ++k) {       // inner: full unroll, static norm
            const unsigned* ch = elds[cc * 4 + k];
            const uint4 f00 = *(const uint4*)(ch + n * 4);              // q0 h0
            const uint4 f01 = *(const uint4*)(ch + (n + 32) * 4);       // q0 h1
            const uint4 f10 = *(const uint4*)(ch + 256 + n * 4);        // q1 h0
            const uint4 f11 = *(const uint4*)(ch + 256 + (n + 32) * 4); // q1 h1

            float p0 = 0.f, p1 = 0.f, p2 = 0.f, p3 = 0.f;
            ACC8(f00, 0)  ACC8(f01, 4)  ACC8(f10, 16) ACC8(f11, 20)
            const float part = (p0 + p1) + (p2 + p3);   // full column sum

            abuf[n] = part;                 // broadcast (same-wave, in-order DS)
            #pragma unroll
            for (int kk = 0; kk < 8; ++kk) {
                const float4 t = *(const float4*)&abuf[kk * 4];
                Ar[4 * kk] = t.x; Ar[4 * kk + 1] = t.y;
                Ar[4 * kk + 2] = t.z; Ar[4 * kk + 3] = t.w;
            }
            if (k == 3) {                   // local norm: no cross-lane
                float mm = Ar[0];
                #pragma unroll
                for (int r = 1; r < 32; ++r) mm = fmaxf(mm, Ar[r]);
                const float rn = __builtin_amdgcn_rcpf(mm);
                #pragma unroll
                for (int r = 0; r < 32; ++r) Ar[r] *= rn;
                Lacc += __logf(mm);
            }
        }
    }
    #undef ACC8

    // z = sum_r Ar[r] * exp(endT[r])  — wave-uniform loads, fully local
    float z = 0.f;
    #pragma unroll
    for (int k = 0; k < 8; ++k) {
        const float4 t = *(const float4*)&endT[k * 4];
        z = fmaf(Ar[4 * k],     __expf(t.x), z);
        z = fmaf(Ar[4 * k + 1], __expf(t.y), z);
        z = fmaf(Ar[4 * k + 2], __expf(t.z), z);
        z = fmaf(Ar[4 * k + 3], __expf(t.w), z);
    }

    #pragma unroll
    for (int d = 16; d > 0; d >>= 1) {
        ntot += __shfl_xor(ntot, d, 32);
        msum += __shfl_xor(msum, d, 32);
        scor += __shfl_xor(scor, d, 32);
    }
    if (lane == 0) {
        const int len = (int)(msum + 0.5f);
        const int lt  = tags[b * S_N + len - 1];
        const float res = Lacc + __logf(z) + ntot * SCALE_LOG - endT[lt] - scor;
        wspart[WS_RES_OFF + b] = res;       // plain store: zero contention
    }
}

// 1 wave: sum the 512 per-block results, write out
__global__ __launch_bounds__(64) void crf_reduce(
    const float* __restrict__ wspart, float* __restrict__ out)
{
    const int lane = threadIdx.x;
    float x = 0.f;
    #pragma unroll
    for (int i = 0; i < 8; ++i) x += wspart[WS_RES_OFF + lane + i * 64];
    #pragma unroll
    for (int d = 32; d > 0; d >>= 1) x += __shfl_xor(x, d, 64);
    if (lane == 0) out[0] = x;
}

extern "C" void kernel_launch(void* const* d_in, const int* in_sizes, int n_in,
                              void* d_out, int out_size, void* d_ws, size_t ws_size,
                              hipStream_t stream) {
    const float* em     = (const float*)d_in[0];
    const int*   tags   = (const int*)  d_in[1];
    const float* mask   = (const float*)d_in[2];
    const float* trans  = (const float*)d_in[3];
    const float* startT = (const float*)d_in[4];
    const float* endT   = (const float*)d_in[5];

    // one block per batch: 8 waves x 4 chunks; 64 KiB LDS -> 2 blocks/CU
    hipLaunchKernelGGL(crf_fused, dim3(B_N), dim3(512), 0, stream,
                       em, tags, mask, trans, startT, endT,
                       (float*)d_ws, (float*)d_out);
    // tiny follow-up: contention-free sum of the 512 block results
    hipLaunchKernelGGL(crf_reduce, dim3(1), dim3(64), 0, stream,
                       (const float*)d_ws, (float*)d_out);
}

// Round 10
// 139.219 us; speedup vs baseline: 1.0529x; 1.0003x over previous
//
#include <hip/hip_runtime.h>
#include <hip/hip_fp16.h>

// CRF NLL on MI355X — round 19: 4-chain interleaved chunk phase.
//
// r18 post-mortem: atomic-drain removal helped (dur_us 141.4->139.3, best).
// rocprof's "81us" was a DVFS artifact — hbm_gbps/MfmaUtil/dur all scaled
// ~1.45x together => lower clock during that profiling pass, not a real
// regression. dur_us from the timing run is ground truth.
//
// Remaining lever: the chunk chain's serial step D -> pack(32 VALU cy) ->
// 2xMFMA(~16cy + forwarding) -> D. With 2 interleaved chains the MFMA
// shadow is only half-filled; r19 restores the r9-proven 4-chain
// interleave (3 other packs = 96 VALU-cy fully cover each chain's MFMA
// latency). Costs: pair-1 loads no longer hide under chain2(pair0)
// (~0.3us, covered by 16-wave TLP); 4x f32x16 accumulators (AGPR-resident,
// r9 ran this at VGPR_Count=64). Staging, replicated-alpha combine,
// plain-store epilogue + 1-wave reduce kernel: byte-identical to r18.
//
// ws layout (dwords): [0,16384) per-wave score/msum/napp slots (b*32+w*4);
//   [16384, 16896) per-block results.
//
// Scale 2^-6.5 per applied matrix (exact: added back as napp*6.5*ln2).

typedef __attribute__((ext_vector_type(8)))  _Float16 half8;
typedef __attribute__((ext_vector_type(2)))  _Float16 half2v;
typedef __attribute__((ext_vector_type(16))) float    f32x16;
typedef __attribute__((ext_vector_type(4)))  unsigned uint4v;

#define S_N 1024
#define T_N 32
#define B_N 512
#define L_CH 32
#define C_CH 32
#define SCALE_MUL 0.011048543456039806f   // 2^-6.5 folded into ee
#define SCALE_LOG 4.505456673639645f      // 6.5*ln2 per applied matrix

#define WS_RES_OFF 16384                  // dword offset of per-block results

__device__ __forceinline__ unsigned pkrtz(float lo, float hi) {
    return __builtin_bit_cast(unsigned, __builtin_amdgcn_cvt_pkrtz(lo, hi));
}
__device__ __forceinline__ unsigned pmul(unsigned a, unsigned b) {
    const __half2 r = __builtin_bit_cast(__half2, a) * __builtin_bit_cast(__half2, b);
    return __builtin_bit_cast(unsigned, r);
}
__device__ __forceinline__ half8 mkh8(const unsigned* a) {
    uint4v u = {a[0], a[1], a[2], a[3]};
    return __builtin_bit_cast(half8, u);
}
__device__ __forceinline__ float hlo(unsigned u) {
    return (float)__builtin_bit_cast(half2v, u).x;
}
__device__ __forceinline__ float hhi(unsigned u) {
    return (float)__builtin_bit_cast(half2v, u).y;
}
// PI: involution swapping rows 4-7<->8-11 and 20-23<->24-27
__device__ __forceinline__ int PIx(int x) { return (x & ~12) | ((x & 4) << 1) | ((x & 8) >> 1); }

__device__ __forceinline__ f32x16 packmm(const f32x16& D, uint4 su, uint4 sv,
                                         half8 A1v, half8 A2v) {
    unsigned S[8];
    S[0] = pmul(pkrtz(D[0],  D[1]),  su.x);
    S[1] = pmul(pkrtz(D[2],  D[3]),  su.y);
    S[2] = pmul(pkrtz(D[4],  D[5]),  su.z);
    S[3] = pmul(pkrtz(D[6],  D[7]),  su.w);
    S[4] = pmul(pkrtz(D[8],  D[9]),  sv.x);
    S[5] = pmul(pkrtz(D[10], D[11]), sv.y);
    S[6] = pmul(pkrtz(D[12], D[13]), sv.z);
    S[7] = pmul(pkrtz(D[14], D[15]), sv.w);
    const f32x16 Z = {};
    f32x16 t = __builtin_amdgcn_mfma_f32_32x32x16_f16(A1v, mkh8(&S[0]), Z, 0, 0, 0);
    return   __builtin_amdgcn_mfma_f32_32x32x16_f16(A2v, mkh8(&S[4]), t, 0, 0, 0);
}
__device__ __forceinline__ void step1(f32x16& D, const unsigned* mq, int r, int h,
                                      half8 A1v, half8 A2v) {
    const uint4 su = *(const uint4*)(mq + r * 16 + h * 8);
    const uint4 sv = *(const uint4*)(mq + r * 16 + h * 8 + 4);
    D = packmm(D, su, sv, A1v, A2v);
}

template<bool CLEAN>
__device__ __forceinline__ void chain4(
    const unsigned* m0, const unsigned* m1,
    const unsigned* m2, const unsigned* m3,
    f32x16& D0, f32x16& D1, f32x16& D2, f32x16& D3,
    unsigned mb0, unsigned mb1, unsigned mb2, unsigned mb3,
    int h, half8 A1v, half8 A2v) {
    if (CLEAN) {
        #pragma unroll 2
        for (int r = L_CH - 1; r >= 1; --r) {
            // all 8 loads issue back-to-back; chains q+1..q+3's packs fill
            // chain q's MFMA shadow (96 VALU-cy vs ~64cy MFMA+fwd latency)
            const uint4 su0 = *(const uint4*)(m0 + r * 16 + h * 8);
            const uint4 sv0 = *(const uint4*)(m0 + r * 16 + h * 8 + 4);
            const uint4 su1 = *(const uint4*)(m1 + r * 16 + h * 8);
            const uint4 sv1 = *(const uint4*)(m1 + r * 16 + h * 8 + 4);
            const uint4 su2 = *(const uint4*)(m2 + r * 16 + h * 8);
            const uint4 sv2 = *(const uint4*)(m2 + r * 16 + h * 8 + 4);
            const uint4 su3 = *(const uint4*)(m3 + r * 16 + h * 8);
            const uint4 sv3 = *(const uint4*)(m3 + r * 16 + h * 8 + 4);
            D0 = packmm(D0, su0, sv0, A1v, A2v);
            D1 = packmm(D1, su1, sv1, A1v, A2v);
            D2 = packmm(D2, su2, sv2, A1v, A2v);
            D3 = packmm(D3, su3, sv3, A1v, A2v);
        }
        if (mb0 & 1u) step1(D0, m0, 0, h, A1v, A2v);   // chunk 0 has bit0 cleared
        if (mb1 & 1u) step1(D1, m1, 0, h, A1v, A2v);
        if (mb2 & 1u) step1(D2, m2, 0, h, A1v, A2v);
        if (mb3 & 1u) step1(D3, m3, 0, h, A1v, A2v);
    } else {
        for (int r = L_CH - 1; r >= 0; --r) {
            if ((mb0 >> r) & 1u) step1(D0, m0, r, h, A1v, A2v);
            if ((mb1 >> r) & 1u) step1(D1, m1, r, h, A1v, A2v);
            if ((mb2 >> r) & 1u) step1(D2, m2, r, h, A1v, A2v);
            if ((mb3 >> r) & 1u) step1(D3, m3, r, h, A1v, A2v);
        }
    }
}

__global__ __attribute__((amdgpu_flat_work_group_size(512, 512),
                          amdgpu_waves_per_eu(4, 4)))
void crf_fused(
    const float* __restrict__ em, const int* __restrict__ tags,
    const float* __restrict__ mask, const float* __restrict__ trans,
    const float* __restrict__ startT, const float* __restrict__ endT,
    float* __restrict__ wspart, float* __restrict__ out)
{
    __shared__ unsigned elds[C_CH][512];   // 64 KiB: scales, reused for fragments
    __shared__ float abuf[32];             // alpha broadcast buffer (combine)

    const int wib  = threadIdx.x >> 6;     // 0..7
    const int lane = threadIdx.x & 63;
    const int n    = lane & 31;
    const int h    = lane >> 5;
    const int b    = blockIdx.x;
    const int c0   = wib * 4;              // this wave's first chunk

    // ---- issue pair-0 emission loads immediately (16B/lane, linear) ----
    float4 P0[4], P1[4];
    {
        const float4* eq0 = (const float4*)(em + ((size_t)b * S_N + (c0 + 0) * L_CH) * T_N);
        const float4* eq1 = (const float4*)(em + ((size_t)b * S_N + (c0 + 1) * L_CH) * T_N);
        #pragma unroll
        for (int i = 0; i < 4; ++i) P0[i] = eq0[i * 64 + lane];
        #pragma unroll
        for (int i = 0; i < 4; ++i) P1[i] = eq1[i * 64 + lane];
    }

    // ---- mask ballots (4 chunks = 128 positions) + path-score partial ----
    unsigned mb_[4];
    {
        float vacc = 0.f, macc = 0.f;
        #pragma unroll
        for (int q2 = 0; q2 < 2; ++q2) {
            const int s  = c0 * L_CH + q2 * 64 + lane;
            const float mv = mask[b * S_N + s];
            const unsigned long long mb = __ballot(mv != 0.0f);
            mb_[2 * q2]     = (unsigned)mb;
            mb_[2 * q2 + 1] = (unsigned)(mb >> 32);
            const int tc = tags[b * S_N + s];
            int tp = __shfl_up(tc, 1, 64);
            float val;
            if (lane == 0) {
                if (s == 0) {
                    val = startT[tc] + em[(size_t)b * S_N * T_N + tc];
                } else {
                    tp = tags[b * S_N + s - 1];
                    val = mv * (em[((size_t)b * S_N + s) * T_N + tc] + trans[tp * 32 + tc]);
                }
            } else {
                val = mv * (em[((size_t)b * S_N + s) * T_N + tc] + trans[tp * 32 + tc]);
            }
            vacc += val; macc += mv;
        }
        if (c0 == 0) mb_[0] &= ~1u;        // t=0 has no transition matrix
        #pragma unroll
        for (int d = 32; d > 0; d >>= 1) {
            vacc += __shfl_xor(vacc, d, 64);
            macc += __shfl_xor(macc, d, 64);
        }
        if (lane == 0) {
            float* slot = wspart + (size_t)b * 32 + wib * 4;
            slot[0] = vacc;
            slot[1] = macc;
            slot[2] = (float)(__popc(mb_[0]) + __popc(mb_[1]) +
                              __popc(mb_[2]) + __popc(mb_[3]));
        }
    }

    // pack loaded f32 quads -> f16 scale pairs in D-reg-pair LDS order.
    #define PACKQ(P, qc) { \
        unsigned* mq = elds[qc]; \
        _Pragma("unroll") \
        for (int i = 0; i < 4; ++i) { \
            const int f = i * 64 + lane; \
            const int r_ = f >> 3; \
            const int m_ = ((f & 1) << 3) | (f & 6); \
            const unsigned pk0 = pkrtz(__expf(P[i].x) * SCALE_MUL, __expf(P[i].y) * SCALE_MUL); \
            const unsigned pk1 = pkrtz(__expf(P[i].z) * SCALE_MUL, __expf(P[i].w) * SCALE_MUL); \
            *(uint2*)(mq + r_ * 16 + m_) = make_uint2(pk0, pk1); \
        } }

    PACKQ(P0, c0)
    PACKQ(P1, c0 + 1)

    // ---- issue pair-1 loads; latency covered by A-frag setup + D-init ----
    {
        const float4* eq2 = (const float4*)(em + ((size_t)b * S_N + (c0 + 2) * L_CH) * T_N);
        const float4* eq3 = (const float4*)(em + ((size_t)b * S_N + (c0 + 3) * L_CH) * T_N);
        #pragma unroll
        for (int i = 0; i < 4; ++i) P0[i] = eq2[i * 64 + lane];
        #pragma unroll
        for (int i = 0; i < 4; ++i) P1[i] = eq3[i * 64 + lane];
    }

    // ---- loop-invariant A fragments: f16(exp(trans)), PI-permuted cols ----
    unsigned A1[4], A2[4];
    #pragma unroll
    for (int j = 0; j < 4; ++j) {
        const int k1 = PIx(8 * h + 2 * j);
        const int k2 = PIx(16 + 8 * h + 2 * j);
        A1[j] = pkrtz(__expf(trans[n * 32 + k1]), __expf(trans[n * 32 + k1 + 1]));
        A2[j] = pkrtz(__expf(trans[n * 32 + k2]), __expf(trans[n * 32 + k2 + 1]));
    }
    const half8 A1v = mkh8(A1), A2v = mkh8(A2);

    // ---- 4 chain states: identity in C layout (AGPR-resident) ----
    f32x16 D0, D1, D2, D3;
    #pragma unroll
    for (int i = 0; i < 16; ++i) {
        const int row = (i & 3) + 8 * (i >> 2) + 4 * h;
        const float v = (row == n) ? 1.0f : 0.0f;
        D0[i] = v; D1[i] = v; D2[i] = v; D3[i] = v;
    }

    PACKQ(P0, c0 + 2)
    PACKQ(P1, c0 + 3)
    #undef PACKQ

    const bool allclean =
        ((mb_[0] | (c0 == 0 ? 1u : 0u)) == 0xFFFFFFFFu) &&
        (mb_[1] == 0xFFFFFFFFu) && (mb_[2] == 0xFFFFFFFFu) && (mb_[3] == 0xFFFFFFFFu);

    if (allclean)
        chain4<true >(elds[c0], elds[c0 + 1], elds[c0 + 2], elds[c0 + 3],
                      D0, D1, D2, D3, mb_[0], mb_[1], mb_[2], mb_[3], h, A1v, A2v);
    else
        chain4<false>(elds[c0], elds[c0 + 1], elds[c0 + 2], elds[c0 + 3],
                      D0, D1, D2, D3, mb_[0], mb_[1], mb_[2], mb_[3], h, A1v, A2v);

    // fragment store: own LDS rows (scales dead), dense SoA, stride-16B
    #define STOREF(D, qc) { \
        unsigned* dst = elds[qc]; \
        ((uint4*)dst)[lane]      = make_uint4(pkrtz(D[0], D[1]),   pkrtz(D[2], D[3]), \
                                              pkrtz(D[4], D[5]),   pkrtz(D[6], D[7])); \
        ((uint4*)dst)[64 + lane] = make_uint4(pkrtz(D[8], D[9]),   pkrtz(D[10], D[11]), \
                                              pkrtz(D[12], D[13]), pkrtz(D[14], D[15])); \
    }
    STOREF(D0, c0) STOREF(D1, c0 + 1) STOREF(D2, c0 + 2) STOREF(D3, c0 + 3)
    #undef STOREF

    __syncthreads();                        // all fragments + ws slots visible

    if (wib != 0) return;

    // ---- combine: replicated-alpha chain, zero cross-lane in the loop ----
    float scor = (lane < 8) ? wspart[(size_t)b * 32 + lane * 4]     : 0.0f;
    float msum = (lane < 8) ? wspart[(size_t)b * 32 + lane * 4 + 1] : 0.0f;
    float ntot = (lane < 8) ? wspart[(size_t)b * 32 + lane * 4 + 2] : 0.0f;

    // init: replicate a0 via abuf (both halves write identical values)
    float Ar[32];
    {
        const float a0 = startT[n] + em[(size_t)b * S_N * T_N + n];
        abuf[n] = a0;
        #pragma unroll
        for (int k = 0; k < 8; ++k) {
            const float4 t = *(const float4*)&abuf[k * 4];
            Ar[4 * k] = t.x; Ar[4 * k + 1] = t.y; Ar[4 * k + 2] = t.z; Ar[4 * k + 3] = t.w;
        }
    }
    float mx = Ar[0];
    #pragma unroll
    for (int r = 1; r < 32; ++r) mx = fmaxf(mx, Ar[r]);
    float Lacc = mx;
    #pragma unroll
    for (int r = 0; r < 32; ++r) Ar[r] = __expf(Ar[r] - mx);

    // row tables are compile-time: fragment half j of quad q, half-block hh
    // covers row (j&3) + 8*(j>>2) + 4*hh + 16*q  (PI already folded in).
    #define ACC8(f, B) { \
        p0 = fmaf(Ar[(B) + 0],  hlo((f).x), p0); \
        p1 = fmaf(Ar[(B) + 1],  hhi((f).x), p1); \
        p2 = fmaf(Ar[(B) + 2],  hlo((f).y), p2); \
        p3 = fmaf(Ar[(B) + 3],  hhi((f).y), p3); \
        p0 = fmaf(Ar[(B) + 8],  hlo((f).z), p0); \
        p1 = fmaf(Ar[(B) + 9],  hhi((f).z), p1); \
        p2 = fmaf(Ar[(B) + 10], hlo((f).w), p2); \
        p3 = fmaf(Ar[(B) + 11], hhi((f).w), p3); }

    for (int cc = 0; cc < 8; ++cc) {        // outer: no unroll (reg pressure)
        #pragma unroll
        for (int k = 0; k < 4; ++k) {       // inner: full unroll, static norm
            const unsigned* ch = elds[cc * 4 + k];
            const uint4 f00 = *(const uint4*)(ch + n * 4);              // q0 h0
            const uint4 f01 = *(const uint4*)(ch + (n + 32) * 4);       // q0 h1
            const uint4 f10 = *(const uint4*)(ch + 256 + n * 4);        // q1 h0
            const uint4 f11 = *(const uint4*)(ch + 256 + (n + 32) * 4); // q1 h1

            float p0 = 0.f, p1 = 0.f, p2 = 0.f, p3 = 0.f;
            ACC8(f00, 0)  ACC8(f01, 4)  ACC8(f10, 16) ACC8(f11, 20)
            const float part = (p0 + p1) + (p2 + p3);   // full column sum

            abuf[n] = part;                 // broadcast (same-wave, in-order DS)
            #pragma unroll
            for (int kk = 0; kk < 8; ++kk) {
                const float4 t = *(const float4*)&abuf[kk * 4];
                Ar[4 * kk] = t.x; Ar[4 * kk + 1] = t.y;
                Ar[4 * kk + 2] = t.z; Ar[4 * kk + 3] = t.w;
            }
            if (k == 3) {                   // local norm: no cross-lane
                float mm = Ar[0];
                #pragma unroll
                for (int r = 1; r < 32; ++r) mm = fmaxf(mm, Ar[r]);
                const float rn = __builtin_amdgcn_rcpf(mm);
                #pragma unroll
                for (int r = 0; r < 32; ++r) Ar[r] *= rn;
                Lacc += __logf(mm);
            }
        }
    }
    #undef ACC8

    // z = sum_r Ar[r] * exp(endT[r])  — wave-uniform loads, fully local
    float z = 0.f;
    #pragma unroll
    for (int k = 0; k < 8; ++k) {
        const float4 t = *(const float4*)&endT[k * 4];
        z = fmaf(Ar[4 * k],     __expf(t.x), z);
        z = fmaf(Ar[4 * k + 1], __expf(t.y), z);
        z = fmaf(Ar[4 * k + 2], __expf(t.z), z);
        z = fmaf(Ar[4 * k + 3], __expf(t.w), z);
    }

    #pragma unroll
    for (int d = 16; d > 0; d >>= 1) {
        ntot += __shfl_xor(ntot, d, 32);
        msum += __shfl_xor(msum, d, 32);
        scor += __shfl_xor(scor, d, 32);
    }
    if (lane == 0) {
        const int len = (int)(msum + 0.5f);
        const int lt  = tags[b * S_N + len - 1];
        const float res = Lacc + __logf(z) + ntot * SCALE_LOG - endT[lt] - scor;
        wspart[WS_RES_OFF + b] = res;       // plain store: zero contention
    }
}

// 1 wave: sum the 512 per-block results, write out
__global__ __launch_bounds__(64) void crf_reduce(
    const float* __restrict__ wspart, float* __restrict__ out)
{
    const int lane = threadIdx.x;
    float x = 0.f;
    #pragma unroll
    for (int i = 0; i < 8; ++i) x += wspart[WS_RES_OFF + lane + i * 64];
    #pragma unroll
    for (int d = 32; d > 0; d >>= 1) x += __shfl_xor(x, d, 64);
    if (lane == 0) out[0] = x;
}

extern "C" void kernel_launch(void* const* d_in, const int* in_sizes, int n_in,
                              void* d_out, int out_size, void* d_ws, size_t ws_size,
                              hipStream_t stream) {
    const float* em     = (const float*)d_in[0];
    const int*   tags   = (const int*)  d_in[1];
    const float* mask   = (const float*)d_in[2];
    const float* trans  = (const float*)d_in[3];
    const float* startT = (const float*)d_in[4];
    const float* endT   = (const float*)d_in[5];

    // one block per batch: 8 waves x 4 chunks (4-chain interleave);
    // 64 KiB LDS -> 2 blocks/CU, 16 waves/CU
    hipLaunchKernelGGL(crf_fused, dim3(B_N), dim3(512), 0, stream,
                       em, tags, mask, trans, startT, endT,
                       (float*)d_ws, (float*)d_out);
    // tiny follow-up: contention-free sum of the 512 block results
    hipLaunchKernelGGL(crf_reduce, dim3(1), dim3(64), 0, stream,
                       (const float*)d_ws, (float*)d_out);
}